// Round 5
// baseline (689.805 us; speedup 1.0000x reference)
//
#include <hip/hip_runtime.h>
#include <hip/hip_bf16.h>

#define N_B 1024
#define N_ITEMS 100000
#define N_CLUSTERS 10
#define N_D 64
#define N_JT (N_ITEMS / 16)   // 6250 j-tiles of 16 items
#define GY 98                 // j-split blocks

typedef __attribute__((ext_vector_type(8))) short short8;
typedef __attribute__((ext_vector_type(4))) float f32x4;

// bf16 RNE split helpers (bit-level; sign-safe)
__device__ __forceinline__ unsigned short bf16_rne(float x) {
  unsigned u = __float_as_uint(x);
  u += 0x7FFFu + ((u >> 16) & 1u);
  return (unsigned short)(u >> 16);
}
__device__ __forceinline__ float bf16_f(unsigned short b) {
  return __uint_as_float(((unsigned)b) << 16);
}

// ---------------------------------------------------------------------------
// Kernel 1: S1[c][d] = sum_{i in c} W1[i][d]; counts[c]. (unchanged from R4)
// ---------------------------------------------------------------------------
__global__ __launch_bounds__(256) void k1_segsum(
    const int* __restrict__ cl, const float* __restrict__ W1,
    float* __restrict__ S1g, float* __restrict__ cntg) {
  __shared__ float s1[4][N_CLUSTERS][N_D];
  __shared__ float scnt[4][N_CLUSTERS];
  int t = threadIdx.x;
  int wave = t >> 6, lane = t & 63;

  float a[N_CLUSTERS], cn[N_CLUSTERS];
#pragma unroll
  for (int k = 0; k < N_CLUSTERS; ++k) { a[k] = 0.f; cn[k] = 0.f; }

  int gw = blockIdx.x * 4 + wave;
  int nw = gridDim.x * 4;
#pragma unroll 4
  for (int i = gw; i < N_ITEMS; i += nw) {
    int c = cl[i];
    float w = W1[(size_t)i * N_D + lane];
#pragma unroll
    for (int k = 0; k < N_CLUSTERS; ++k) {
      bool m = (c == k);
      a[k] += m ? w : 0.f;
      cn[k] += m ? 1.f : 0.f;
    }
  }
#pragma unroll
  for (int k = 0; k < N_CLUSTERS; ++k) s1[wave][k][lane] = a[k];
  if (lane == 0) {
#pragma unroll
    for (int k = 0; k < N_CLUSTERS; ++k) scnt[wave][k] = cn[k];
  }
  __syncthreads();
  const float* fs1 = (const float*)s1;
  for (int i = t; i < N_CLUSTERS * N_D; i += 256) {
    float v = fs1[i] + fs1[640 + i] + fs1[1280 + i] + fs1[1920 + i];
    atomicAdd(&S1g[i], v);
  }
  if (t < N_CLUSTERS) {
    float v = scnt[0][t] + scnt[1][t] + scnt[2][t] + scnt[3][t];
    atomicAdd(&cntg[t], v);
  }
}

// ---------------------------------------------------------------------------
// Kernel 2: h[row][d] = sum_c input[row][c] * S1[c][d]   (1024 x 64 row-major)
// ---------------------------------------------------------------------------
__global__ __launch_bounds__(256) void k2_h(
    const float* __restrict__ inp, const float* __restrict__ S1g,
    float* __restrict__ h) {
  int idx = blockIdx.x * 256 + threadIdx.x;   // 65536 exactly
  int row = idx >> 6, d = idx & 63;
  float acc = 0.f;
#pragma unroll
  for (int c = 0; c < N_CLUSTERS; ++c)
    acc += inp[row * N_CLUSTERS + c] * S1g[c * N_D + d];
  h[idx] = acc;
}

// ---------------------------------------------------------------------------
// Kernel 2b: build A-operand MFMA fragments of h, split into bf16 hi/lo.
// A layout (16x16x32): lane holds A[m=lane&15][k=(lane>>4)*8 + j], j=0..7.
// hfrag[((rt*2+ks)*2+term)*64 + lane] : short8.
// ---------------------------------------------------------------------------
__global__ __launch_bounds__(256) void k2b_frag(
    const float* __restrict__ h, short8* __restrict__ hfrag) {
  int id = blockIdx.x * 256 + threadIdx.x;    // 8192 = 64rt * 2ks * 64lane
  int lane = id & 63;
  int ks = (id >> 6) & 1;
  int rt = id >> 7;                            // 0..63
  int row = rt * 16 + (lane & 15);
  int d0 = ks * 32 + (lane >> 4) * 8;
  short8 hi, lo;
#pragma unroll
  for (int j = 0; j < 8; ++j) {
    float x = h[row * N_D + d0 + j];
    unsigned short us = bf16_rne(x);
    hi[j] = (short)us;
    lo[j] = (short)bf16_rne(x - bf16_f(us));
  }
  hfrag[((rt * 2 + ks) * 2 + 0) * 64 + lane] = hi;
  hfrag[((rt * 2 + ks) * 2 + 1) * 64 + lane] = lo;
}

// ---------------------------------------------------------------------------
// Kernel 3 (hot): split-bf16 MFMA logits + exp + LDS bucket accumulation.
// Block = 64 rows (4 row-tiles; A-frags resident in 64 VGPRs) x j-tile stream.
// Per j-tile/wave: 16 coalesced fp32 W2 loads directly in B-frag order
// (B[k=(lane>>4)*8+j][n=lane&15]), cvt to bf16 hi/lo, 6 MFMAs per row-tile
// (hh+hl+lh over 2 k-steps), exp, ds_atomic into x4-replicated bucket.
// ---------------------------------------------------------------------------
__global__ __launch_bounds__(256) void k3_mfma(
    const float* __restrict__ W2, const short8* __restrict__ hfrag,
    const int* __restrict__ cl, float* __restrict__ bucketg) {
  __shared__ float bkt[64][N_CLUSTERS * 4];   // 10240 B
  int t = threadIdx.x;
  int wave = t >> 6, lane = t & 63;
  int quad = lane >> 4, l15 = lane & 15;

  for (int i = t; i < 64 * N_CLUSTERS * 4; i += 256) ((float*)bkt)[i] = 0.f;

  // Resident A-fragments: 4 row-tiles x 2 k-steps x {hi,lo} = 64 VGPRs
  short8 af[4][2][2];
#pragma unroll
  for (int rt = 0; rt < 4; ++rt)
#pragma unroll
    for (int ks = 0; ks < 2; ++ks)
#pragma unroll
      for (int tm = 0; tm < 2; ++tm)
        af[rt][ks][tm] =
            hfrag[(((blockIdx.x * 4 + rt) * 2 + ks) * 2 + tm) * 64 + lane];
  __syncthreads();

  const float* __restrict__ wbase = W2 + (size_t)(quad * 8) * N_ITEMS + l15;

  for (int jt = blockIdx.y * 4 + wave; jt < N_JT; jt += GY * 4) {
    int j0 = jt * 16;
    int cc = cl[j0 + l15];                    // this lane's item-col cluster
    int slot = cc * 4 + (lane & 3);           // x4 replication: <=2-way dupes

    float w0[8], w1[8];
#pragma unroll
    for (int j = 0; j < 8; ++j) w0[j] = wbase[(size_t)j * N_ITEMS + j0];
#pragma unroll
    for (int j = 0; j < 8; ++j) w1[j] = wbase[(size_t)(32 + j) * N_ITEMS + j0];

    short8 bh0, bl0, bh1, bl1;
#pragma unroll
    for (int j = 0; j < 8; ++j) {
      unsigned short us = bf16_rne(w0[j]);
      bh0[j] = (short)us;
      bl0[j] = (short)bf16_rne(w0[j] - bf16_f(us));
    }
#pragma unroll
    for (int j = 0; j < 8; ++j) {
      unsigned short us = bf16_rne(w1[j]);
      bh1[j] = (short)us;
      bl1[j] = (short)bf16_rne(w1[j] - bf16_f(us));
    }

#pragma unroll
    for (int rt = 0; rt < 4; ++rt) {
      f32x4 c = {0.f, 0.f, 0.f, 0.f};
      c = __builtin_amdgcn_mfma_f32_16x16x32_bf16(af[rt][0][0], bh0, c, 0, 0, 0);
      c = __builtin_amdgcn_mfma_f32_16x16x32_bf16(af[rt][0][0], bl0, c, 0, 0, 0);
      c = __builtin_amdgcn_mfma_f32_16x16x32_bf16(af[rt][0][1], bh0, c, 0, 0, 0);
      c = __builtin_amdgcn_mfma_f32_16x16x32_bf16(af[rt][1][0], bh1, c, 0, 0, 0);
      c = __builtin_amdgcn_mfma_f32_16x16x32_bf16(af[rt][1][0], bl1, c, 0, 0, 0);
      c = __builtin_amdgcn_mfma_f32_16x16x32_bf16(af[rt][1][1], bh1, c, 0, 0, 0);
      // C/D: col = lane&15 (item), row = quad*4 + reg  [m89-verified]
#pragma unroll
      for (int reg = 0; reg < 4; ++reg)
        atomicAdd(&bkt[rt * 16 + quad * 4 + reg][slot], __expf(c[reg]));
    }
  }
  __syncthreads();

  for (int i = t; i < 64 * N_CLUSTERS; i += 256) {
    int r = i / N_CLUSTERS, c = i % N_CLUSTERS;
    float v = bkt[r][c * 4] + bkt[r][c * 4 + 1] + bkt[r][c * 4 + 2] +
              bkt[r][c * 4 + 3];
    atomicAdd(&bucketg[(size_t)(blockIdx.x * 64 + r) * N_CLUSTERS + c], v);
  }
}

// ---------------------------------------------------------------------------
// Kernel 4: out[b][c] = bucket[b][c] / (sum_c' bucket[b][c']) / max(cnt[c],1)
// ---------------------------------------------------------------------------
__global__ __launch_bounds__(256) void k4_fin(
    const float* __restrict__ bucketg, const float* __restrict__ cntg,
    float* __restrict__ out) {
  int idx = blockIdx.x * 256 + threadIdx.x;
  if (idx >= N_B * N_CLUSTERS) return;
  int row = idx / N_CLUSTERS, c = idx % N_CLUSTERS;
  const float* b = bucketg + (size_t)row * N_CLUSTERS;
  float total = 0.f;
#pragma unroll
  for (int k = 0; k < N_CLUSTERS; ++k) total += b[k];
  out[idx] = b[c] / (total * fmaxf(cntg[c], 1.f));
}

// ---------------------------------------------------------------------------
// Workspace layout (floats):
//   [0,     640)    S1
//   [640,   650)    counts
//   [1024,  11264)  buckets (1024 x 10)          <- zeroed
//   [12288, 77824)  h (1024 x 64 row-major)
//   [77824, 143360) hfrag (16384 x short8 = 256 KB)
// ---------------------------------------------------------------------------
extern "C" void kernel_launch(void* const* d_in, const int* in_sizes, int n_in,
                              void* d_out, int out_size, void* d_ws, size_t ws_size,
                              hipStream_t stream) {
  const float* input = (const float*)d_in[0];   // (1024, 10) f32
  const int* cl      = (const int*)d_in[1];     // (100000,) i32
  const float* W1    = (const float*)d_in[2];   // (100000, 64) f32
  const float* W2    = (const float*)d_in[3];   // (64, 100000) f32
  float* out = (float*)d_out;
  float* ws = (float*)d_ws;

  float* S1g     = ws;
  float* cntg    = ws + 640;
  float* bucketg = ws + 1024;
  float* h       = ws + 12288;
  short8* hfrag  = (short8*)(ws + 77824);

  hipMemsetAsync(d_ws, 0, (size_t)11264 * sizeof(float), stream);

  k1_segsum<<<512, 256, 0, stream>>>(cl, W1, S1g, cntg);
  k2_h<<<256, 256, 0, stream>>>(input, S1g, h);
  k2b_frag<<<32, 256, 0, stream>>>(h, hfrag);

  dim3 g3(N_B / 64, GY);   // (16, 98)
  k3_mfma<<<g3, 256, 0, stream>>>(W2, hfrag, cl, bucketg);

  k4_fin<<<(N_B * N_CLUSTERS + 255) / 256, 256, 0, stream>>>(bucketg, cntg, out);
}